// Round 1
// baseline (345.220 us; speedup 1.0000x reference)
//
#include <hip/hip_runtime.h>

#define BB 2048
#define NN 200
#define DD 128
#define HH 8

// ---------------------------------------------------------------------------
// Kernel 1: v[b][d] = sum_h Wr[h] * tanh( bq[d*8+h] + dot(q[b,:], Wq[d*8+h,:]) )
// Grid (4 j-chunks x 128 b-chunks), 256 threads. Thread owns one j = d*8+h,
// register-blocks 16 b's. Wq staged transposed in LDS (lane-consecutive reads),
// q read via wave-uniform scalar loads.
// ---------------------------------------------------------------------------
__global__ __launch_bounds__(256) void proj_kernel(
    const float* __restrict__ q,    // (B, 128)
    const float* __restrict__ Wq,   // (1024, 128)
    const float* __restrict__ bq,   // (1024)
    const float* __restrict__ Wr,   // (1, 8)
    float* __restrict__ v)          // (B, 128)
{
    __shared__ float wq_s[32][257];           // [k within tile][j within chunk], padded
    const int t  = threadIdx.x;               // 0..255
    const int jc = blockIdx.x;                // 0..3   -> j chunk of 256
    const int b0 = blockIdx.y * 16;           // 0..2047 in steps of 16
    const int j  = jc * 256 + t;

    float acc[16];
#pragma unroll
    for (int i = 0; i < 16; ++i) acc[i] = 0.f;

    for (int kt = 0; kt < 4; ++kt) {          // k tiles of 32
        __syncthreads();
        // stage Wq[jc*256 .. +255][kt*32 .. +31] transposed into LDS
#pragma unroll
        for (int i = 0; i < 8; ++i) {
            int idx = t + 256 * i;            // 0..2047 f4 slots
            int jj  = idx >> 3;               // 0..255
            int kf  = idx & 7;                // 0..7  (f4 within 32-k row)
            const float4 w4 = *(const float4*)(Wq + (size_t)(jc*256 + jj)*128 + kt*32 + kf*4);
            wq_s[kf*4+0][jj] = w4.x;
            wq_s[kf*4+1][jj] = w4.y;
            wq_s[kf*4+2][jj] = w4.z;
            wq_s[kf*4+3][jj] = w4.w;
        }
        __syncthreads();

        float wreg[32];
#pragma unroll
        for (int k = 0; k < 32; ++k) wreg[k] = wq_s[k][t];   // lane-consecutive: conflict-free

#pragma unroll
        for (int bb = 0; bb < 16; ++bb) {
            const float* qrow = q + (size_t)(b0 + bb)*128 + kt*32;  // wave-uniform -> s_load
            float s = 0.f;
#pragma unroll
            for (int k = 0; k < 32; ++k) s = fmaf(qrow[k], wreg[k], s);
            acc[bb] += s;
        }
    }

    const float bqj = bq[j];
    const float wrh = Wr[j & 7];
    const int   d   = j >> 3;
#pragma unroll
    for (int bb = 0; bb < 16; ++bb) {
        float p = tanhf(acc[bb] + bqj) * wrh;
        // sum over the 8 h-lanes (j = d*8 + h, h = t&7, contiguous in a wave)
        p += __shfl_xor(p, 1);
        p += __shfl_xor(p, 2);
        p += __shfl_xor(p, 4);
        if ((t & 7) == 0) v[(size_t)(b0 + bb)*128 + d] = p;
    }
}

// ---------------------------------------------------------------------------
// Kernel 2: one block per b; online softmax over N=200 in chunks of 64 rows.
// 512 threads. Each half-wave owns one row per load step: coalesced float4
// loads, dot vs register-resident v fragment, shuffle-reduce; row stashed to
// LDS for the weighted-accumulate pass.
// ---------------------------------------------------------------------------
__global__ __launch_bounds__(512) void attn_kernel(
    const float* __restrict__ item,  // (B, 200, 128)
    const int*   __restrict__ mask,  // (B, 200) as int32
    const float* __restrict__ v,     // (B, 128)
    float* __restrict__ out)         // (B, 128)
{
    __shared__ float item_s[64][132];   // padded row stride (528 B, 16B-aligned)
    __shared__ float red_s[64];
    __shared__ float w_s[64];
    __shared__ float o_s[4][128];

    const int t   = threadIdx.x;       // 0..511
    const int b   = blockIdx.x;
    const int seg = t & 31;            // f4 segment within a row
    const int l64 = t & 63;
    const int d   = t & 127;
    const int p   = t >> 7;            // 0..3: row-partition for accumulate

    const float4 vreg  = *(const float4*)(v + (size_t)b*128 + seg*4);
    const float* itemb = item + (size_t)b * (NN * 128);

    float m = -3e38f, lsum = 0.f, o_part = 0.f;

    for (int n0 = 0; n0 < NN; n0 += 64) {
        const int rows = min(64, NN - n0);
        __syncthreads();   // protect item_s/red_s/w_s reuse across chunks

        // ---- load chunk + dot against v ----
#pragma unroll
        for (int i = 0; i < 4; ++i) {
            const int row = (t >> 5) + 16 * i;          // half-wave owns this row
            float4 f4 = make_float4(0.f, 0.f, 0.f, 0.f);
            if (row < rows)
                f4 = *(const float4*)(itemb + (size_t)(n0 + row)*128 + seg*4);
            float pp = f4.x*vreg.x + f4.y*vreg.y + f4.z*vreg.z + f4.w*vreg.w;
#pragma unroll
            for (int off = 16; off >= 1; off >>= 1)     // reduce within 32-lane half
                pp += __shfl_xor(pp, off);
            if (row < rows) {
                *(float4*)(&item_s[row][seg*4]) = f4;   // lane-consecutive f4: conflict-free
                if (seg == 0) red_s[row] = pp;
            }
        }
        __syncthreads();

        // ---- chunk max over ALL rows (unmasked, matches reference) ----
        float mv = (l64 < rows) ? red_s[l64] : -3e38f;
#pragma unroll
        for (int off = 32; off >= 1; off >>= 1)
            mv = fmaxf(mv, __shfl_xor(mv, off));
        const float new_m = fmaxf(m, mv);
        const float alpha = __expf(m - new_m);          // chunk 0: exp(-3e38-x) -> 0
        m = new_m;

        // ---- masked exp weights ----
        if (t < 64) {
            float w = 0.f;
            if (t < rows) {
                const int mk = mask[(size_t)b * NN + n0 + t];
                w = mk ? __expf(red_s[t] - new_m) : 0.f;
            }
            w_s[t] = w;
        }
        __syncthreads();

        // ---- denom update (redundant, wave-uniform result) ----
        float sv = w_s[l64];
#pragma unroll
        for (int off = 32; off >= 1; off >>= 1)
            sv += __shfl_xor(sv, off);
        lsum = lsum * alpha + sv;

        // ---- weighted accumulate: thread owns (d, 16-row partition p) ----
        float acc = 0.f;
#pragma unroll
        for (int nn = 0; nn < 16; ++nn)
            acc = fmaf(w_s[p*16 + nn], item_s[p*16 + nn][d], acc);  // row-broadcast reads
        o_part = o_part * alpha + acc;
    }

    o_s[p][d] = o_part;
    __syncthreads();
    if (t < 128) {
        const float tot   = o_s[0][t] + o_s[1][t] + o_s[2][t] + o_s[3][t];
        const float denom = (lsum < 1e-7f) ? (lsum + 1.f) : lsum;
        out[(size_t)b * 128 + t] = tot / denom;
    }
}

// ---------------------------------------------------------------------------
extern "C" void kernel_launch(void* const* d_in, const int* in_sizes, int n_in,
                              void* d_out, int out_size, void* d_ws, size_t ws_size,
                              hipStream_t stream) {
    const float* item = (const float*)d_in[0];   // (2048, 200, 128)
    const float* q    = (const float*)d_in[1];   // (2048, 128)
    const int*   mask = (const int*)  d_in[2];   // (2048, 200, 1) bool -> int32
    const float* Wq   = (const float*)d_in[3];   // (1024, 128)
    const float* bq   = (const float*)d_in[4];   // (1024)
    const float* Wr   = (const float*)d_in[5];   // (1, 8)
    float* out = (float*)d_out;                  // (2048, 128)
    float* v   = (float*)d_ws;                   // scratch: 2048*128*4 = 1 MiB

    proj_kernel<<<dim3(4, 128), 256, 0, stream>>>(q, Wq, bq, Wr, v);
    attn_kernel<<<dim3(BB), 512, 0, stream>>>(item, mask, v, out);
}

// Round 2
// 343.789 us; speedup vs baseline: 1.0042x; 1.0042x over previous
//
#include <hip/hip_runtime.h>

#define BB 2048
#define NN 200
#define DD 128
#define HH 8

typedef float f4v __attribute__((ext_vector_type(4)));

// ---------------------------------------------------------------------------
// Kernel 1: v[b][d] = sum_h Wr[h] * tanh( bq[d*8+h] + dot(q[b,:], Wq[d*8+h,:]) )
// Grid (4 j-chunks x 128 b-chunks), 256 threads. Thread owns one j = d*8+h,
// register-blocks 16 b's. Wq staged transposed in LDS (lane-consecutive reads),
// q read via wave-uniform scalar loads.  ~537 MFLOP total -> a few us.
// ---------------------------------------------------------------------------
__global__ __launch_bounds__(256) void proj_kernel(
    const float* __restrict__ q,    // (B, 128)
    const float* __restrict__ Wq,   // (1024, 128)
    const float* __restrict__ bq,   // (1024)
    const float* __restrict__ Wr,   // (1, 8)
    float* __restrict__ v)          // (B, 128)
{
    __shared__ float wq_s[32][257];           // [k within tile][j within chunk], padded
    const int t  = threadIdx.x;               // 0..255
    const int jc = blockIdx.x;                // 0..3   -> j chunk of 256
    const int b0 = blockIdx.y * 16;           // 0..2047 in steps of 16
    const int j  = jc * 256 + t;

    float acc[16];
#pragma unroll
    for (int i = 0; i < 16; ++i) acc[i] = 0.f;

    for (int kt = 0; kt < 4; ++kt) {          // k tiles of 32
        __syncthreads();
#pragma unroll
        for (int i = 0; i < 8; ++i) {
            int idx = t + 256 * i;            // 0..2047 f4 slots
            int jj  = idx >> 3;               // 0..255
            int kf  = idx & 7;                // 0..7
            const float4 w4 = *(const float4*)(Wq + (size_t)(jc*256 + jj)*128 + kt*32 + kf*4);
            wq_s[kf*4+0][jj] = w4.x;
            wq_s[kf*4+1][jj] = w4.y;
            wq_s[kf*4+2][jj] = w4.z;
            wq_s[kf*4+3][jj] = w4.w;
        }
        __syncthreads();

        float wreg[32];
#pragma unroll
        for (int k = 0; k < 32; ++k) wreg[k] = wq_s[k][t];   // lane-consecutive: conflict-free

#pragma unroll
        for (int bb = 0; bb < 16; ++bb) {
            const float* qrow = q + (size_t)(b0 + bb)*128 + kt*32;  // wave-uniform -> s_load
            float s = 0.f;
#pragma unroll
            for (int k = 0; k < 32; ++k) s = fmaf(qrow[k], wreg[k], s);
            acc[bb] += s;
        }
    }

    const float bqj = bq[j];
    const float wrh = Wr[j & 7];
    const int   d   = j >> 3;
#pragma unroll
    for (int bb = 0; bb < 16; ++bb) {
        float p = tanhf(acc[bb] + bqj) * wrh;
        p += __shfl_xor(p, 1);
        p += __shfl_xor(p, 2);
        p += __shfl_xor(p, 4);
        if ((t & 7) == 0) v[(size_t)(b0 + bb)*128 + d] = p;
    }
}

// ---------------------------------------------------------------------------
// Kernel 2: one block per b; online softmax over N=200 in 3 chunks {64,64,72}
// (tail folded into last chunk). 512 threads. Half-wave owns one row per load
// step: coalesced nontemporal float4 loads, register-prefetch of the NEXT
// chunk issued before the reduce/accumulate phase (loads-to-VGPR survive
// s_barrier -> HBM latency hidden). Rows stashed in LDS for the weighted-
// accumulate pass; final o-partials overlay item_s rows 0..3.
// LDS ~38.6 KB -> 4 blocks/CU x 8 waves = 32 waves/CU (needs VGPR<=64, hence
// __launch_bounds__(512, 8)).
// ---------------------------------------------------------------------------
__global__ __launch_bounds__(512, 8) void attn_kernel(
    const float* __restrict__ item,  // (B, 200, 128)
    const int*   __restrict__ mask,  // (B, 200) as int32
    const float* __restrict__ v,     // (B, 128)
    float* __restrict__ out)         // (B, 128)
{
    __shared__ float item_s[72][132];   // padded row stride (528 B, 16B-aligned)
    __shared__ float red_s[72];
    __shared__ float w_s[72];

    const int t    = threadIdx.x;      // 0..511
    const int b    = blockIdx.x;
    const int seg  = t & 31;           // f4 segment within a row
    const int half = t >> 5;           // 0..15: half-wave id = row group
    const int l64  = t & 63;
    const int d    = t & 127;
    const int p    = t >> 7;           // 0..3: row-partition for accumulate

    const f4v vreg = *(const f4v*)(v + (size_t)b*128 + seg*4);
    const float* itemb = item + (size_t)b * (NN * 128);

    float m = -3e38f, lsum = 0.f, o_part = 0.f;

    // ---- prefetch chunk 0 into registers ----
    f4v pre[5];
#pragma unroll
    for (int i = 0; i < 5; ++i) {
        const int row = half + 16*i;
        pre[i] = (f4v)0.f;
        if (row < 64)
            pre[i] = __builtin_nontemporal_load(
                (const f4v*)(itemb + (size_t)row*128 + seg*4));
    }

    for (int c = 0; c < 3; ++c) {
        const int base = c * 64;
        const int rows = (c == 2) ? 72 : 64;
        __syncthreads();   // item_s/red_s/w_s free for reuse

        // ---- store prefetched rows to LDS + dot against v ----
#pragma unroll
        for (int i = 0; i < 5; ++i) {
            const int row = half + 16*i;
            if (row < rows) {
                const f4v f = pre[i];
                float pp = f[0]*vreg[0] + f[1]*vreg[1] + f[2]*vreg[2] + f[3]*vreg[3];
#pragma unroll
                for (int off = 16; off >= 1; off >>= 1)      // reduce within 32-lane half
                    pp += __shfl_xor(pp, off);
                *(f4v*)(&item_s[row][seg*4]) = f;            // lane-consecutive f4: conflict-free
                if (seg == 0) red_s[row] = pp;
            }
        }

        // ---- issue next chunk's global loads NOW (hidden under softmax work) ----
        if (c < 2) {
            const int nbase = (c + 1) * 64;
            const int nrows = (c == 1) ? 72 : 64;
#pragma unroll
            for (int i = 0; i < 5; ++i) {
                const int row = half + 16*i;
                pre[i] = (f4v)0.f;
                if (row < nrows)
                    pre[i] = __builtin_nontemporal_load(
                        (const f4v*)(itemb + (size_t)(nbase + row)*128 + seg*4));
            }
        }
        __syncthreads();

        // ---- chunk max over ALL rows (unmasked, matches reference) ----
        float mv = red_s[l64];
        if (c == 2 && l64 < 8) mv = fmaxf(mv, red_s[64 + l64]);
#pragma unroll
        for (int off = 32; off >= 1; off >>= 1)
            mv = fmaxf(mv, __shfl_xor(mv, off));
        const float new_m = fmaxf(m, mv);
        const float alpha = __expf(m - new_m);   // chunk 0: exp(-3e38 - x) -> 0
        m = new_m;

        // ---- masked exp weights ----
        if (t < rows) {
            const int mk = mask[(size_t)b * NN + base + t];
            w_s[t] = mk ? __expf(red_s[t] - new_m) : 0.f;
        }
        __syncthreads();

        // ---- denom update (redundant per wave, uniform result) ----
        float sv = w_s[l64];
        if (c == 2 && l64 < 8) sv += w_s[64 + l64];
#pragma unroll
        for (int off = 32; off >= 1; off >>= 1)
            sv += __shfl_xor(sv, off);
        lsum = lsum * alpha + sv;

        // ---- weighted accumulate: thread owns (d, rows/4 partition p) ----
        const int rpp = rows >> 2;              // 16 or 18
        float acc = 0.f;
#pragma unroll
        for (int nn = 0; nn < 18; ++nn)
            if (nn < rpp)
                acc = fmaf(w_s[p*rpp + nn], item_s[p*rpp + nn][d], acc);
        o_part = o_part * alpha + acc;
    }

    // ---- combine 4 partials per d (overlay onto item_s rows 0..3) ----
    __syncthreads();
    item_s[p][d] = o_part;
    __syncthreads();
    if (t < 128) {
        const float tot   = item_s[0][t] + item_s[1][t] + item_s[2][t] + item_s[3][t];
        const float denom = (lsum < 1e-7f) ? (lsum + 1.f) : lsum;
        out[(size_t)b * 128 + t] = tot / denom;
    }
}

// ---------------------------------------------------------------------------
extern "C" void kernel_launch(void* const* d_in, const int* in_sizes, int n_in,
                              void* d_out, int out_size, void* d_ws, size_t ws_size,
                              hipStream_t stream) {
    const float* item = (const float*)d_in[0];   // (2048, 200, 128)
    const float* q    = (const float*)d_in[1];   // (2048, 128)
    const int*   mask = (const int*)  d_in[2];   // (2048, 200, 1) bool -> int32
    const float* Wq   = (const float*)d_in[3];   // (1024, 128)
    const float* bq   = (const float*)d_in[4];   // (1024)
    const float* Wr   = (const float*)d_in[5];   // (1, 8)
    float* out = (float*)d_out;                  // (2048, 128)
    float* v   = (float*)d_ws;                   // scratch: 2048*128*4 = 1 MiB

    proj_kernel<<<dim3(4, 128), 256, 0, stream>>>(q, Wq, bq, Wr, v);
    attn_kernel<<<dim3(BB), 512, 0, stream>>>(item, mask, v, out);
}